// Round 11
// baseline (326.527 us; speedup 1.0000x reference)
//
#include <hip/hip_runtime.h>

typedef unsigned int u32;
typedef unsigned short u16;

typedef __attribute__((ext_vector_type(8))) short short8v;   // 8 x bf16 bits
typedef __attribute__((ext_vector_type(4))) float f32x4;

#define AS_GLOBAL __attribute__((address_space(1)))
#define AS_LDS    __attribute__((address_space(3)))

static __device__ __forceinline__ u16 f32_bf16_rne(float f) {
  u32 u = __builtin_bit_cast(u32, f);
  u32 lsb = (u >> 16) & 1u;
  u += 0x7fffu + lsb;
  return (u16)(u >> 16);
}

// ---------------------------------------------------------------------------
// Pass 1: quotient-remainder fake quant, f32 -> bf16 bits.
// One group (GS=128) per 16-lane subgroup; 8 elems/lane.
// base >= 2 always, so reference's sel_mask (base < 1.0) is always false.
// ---------------------------------------------------------------------------
__global__ __launch_bounds__(256) void quant_kernel(
    const float* __restrict__ x, u16* __restrict__ xq) {
  const int tid = blockIdx.x * 256 + threadIdx.x;
  const int grp = tid >> 4;
  const int l   = tid & 15;
  const size_t base_e = (size_t)grp * 128;
  const float* gx = x + base_e;

  float4 v0 = *(const float4*)(gx + l * 4);
  float4 v1 = *(const float4*)(gx + 64 + l * 4);
  float xs[8] = {v0.x, v0.y, v0.z, v0.w, v1.x, v1.y, v1.z, v1.w};

  float mabs = 0.f;
  #pragma unroll
  for (int i = 0; i < 8; ++i) mabs = fmaxf(mabs, fabsf(xs[i]));
  #pragma unroll
  for (int s = 1; s < 16; s <<= 1) mabs = fmaxf(mabs, __shfl_xor(mabs, s, 16));
  mabs = fmaxf(mabs, 1e-8f);

  const float thr = mabs / 7.0f;            // true division: matches np
  float base = 64.f;
  base = (thr <= 32.f) ? 32.f : base;
  base = (thr <= 16.f) ? 16.f : base;
  base = (thr <= 8.f)  ? 8.f  : base;
  base = (thr <= 4.f)  ? 4.f  : base;
  base = (thr <= 2.f)  ? 2.f  : base;
  const float rbase = 1.0f / base;          // exact (power of 2)

  float q[8], r[8];
  float mr = 0.f;
  #pragma unroll
  for (int i = 0; i < 8; ++i) {
    float qq = rintf(xs[i] * rbase);        // == rintf(xs/base), exact scale
    qq = fminf(fmaxf(qq, -7.f), 7.f);
    q[i] = qq;
    r[i] = xs[i] - base * qq;               // exact product, IEEE sub
    mr = fmaxf(mr, fabsf(r[i]));
  }
  #pragma unroll
  for (int s = 1; s < 16; s <<= 1) mr = fmaxf(mr, __shfl_xor(mr, s, 16));
  float rs = fmaxf(mr, 1e-8f) / 7.0f;
  rs = fmaxf(rs, 1e-8f);

  u16 o[8];
  #pragma unroll
  for (int i = 0; i < 8; ++i) {
    float rd = rintf(r[i] / rs);            // IEEE division: matches np
    rd = fminf(fmaxf(rd, -8.f), 7.f) * rs;
    o[i] = f32_bf16_rne(q[i] * base + rd);
  }
  uint2 p0, p1;
  p0.x = (u32)o[0] | ((u32)o[1] << 16);
  p0.y = (u32)o[2] | ((u32)o[3] << 16);
  p1.x = (u32)o[4] | ((u32)o[5] << 16);
  p1.y = (u32)o[6] | ((u32)o[7] << 16);
  *(uint2*)(xq + base_e + l * 4) = p0;
  *(uint2*)(xq + base_e + 64 + l * 4) = p1;
}

// ---------------------------------------------------------------------------
// Pass 2: weight f32 -> bf16 bits.
// ---------------------------------------------------------------------------
__global__ __launch_bounds__(256) void wconv_kernel(
    const float* __restrict__ w, u16* __restrict__ wq) {
  const int i = (blockIdx.x * 256 + threadIdx.x) * 4;
  float4 v = *(const float4*)(w + i);
  uint2 p;
  p.x = (u32)f32_bf16_rne(v.x) | ((u32)f32_bf16_rne(v.y) << 16);
  p.y = (u32)f32_bf16_rne(v.z) | ((u32)f32_bf16_rne(v.w) << 16);
  *(uint2*)(wq + i) = p;
}

// ---------------------------------------------------------------------------
// Pass 3: bf16 MFMA GEMM — m97-exact operating point (multi-block/CU TLP):
// 128x128 tile, BK=64, 4 waves (2x2), single-buffered 32 KiB LDS, simple
// drain loop (__syncthreads each K-step). Grid 4096 -> ~16 blocks/CU of
// work, ~3 co-resident (reg budget ~152/wave incl AGPR): when one block
// drains at its barrier, other blocks' waves fill the MFMA/VALU pipes
// (m114 mechanism; m97 measured 874-912 TF with this exact structure).
//
// ROUND-11 CHANGE vs r1 (verified 550 TF, absmax-pass): XCD-GROUPED block
// mapping only. xcd=bid&7, j=bid>>3, mt=xcd*64+(j>>3), nt=j&7: all 8
// nt-blocks of an A-panel land consecutively on ONE XCD -> A fetched once
// per panel (L2-shared), B (2 MB) L2-resident per XCD. r1's FETCH was
// 532 MB (4.2x over-fetch, panels scattered); expect ~140-190 MB.
//
// LDS swizzle (r1-verified): staging chunk = 8 rows x 128B; source slot
// (lane&7)^(lane>>3); read byte col ^ ((l16&7)<<4) -> 8-slot XOR (T2).
// ---------------------------------------------------------------------------
#define BM 128
#define BN 128
#define BK 64

__global__ __launch_bounds__(256) void gemm_kernel(
    const u16* __restrict__ A, const u16* __restrict__ B,
    const float* __restrict__ bias, float* __restrict__ out,
    int M, int N, int K) {
  __shared__ u16 Asm[BM * BK];   // 16 KiB, linear [row][64], swizzled content
  __shared__ u16 Bsm[BN * BK];   // 16 KiB

  const int tid  = threadIdx.x;
  const int w    = tid >> 6;
  const int lane = tid & 63;
  const int l16  = lane & 15;
  const int quad = lane >> 4;

  // XCD-grouped mapping: 8 nt-blocks of each mt contiguous on one XCD
  const int xcd = blockIdx.x & 7;
  const int j   = blockIdx.x >> 3;          // 0..511
  const int mt  = xcd * 64 + (j >> 3);      // 64 mts per XCD
  const int nt  = j & 7;
  const int m0 = mt * BM, n0 = nt * BN;
  const int wm = (w >> 1) * 64, wn = (w & 1) * 64;

  // staging geometry: chunk = 1 KiB = 8 rows of 128B; lane -> (row, slot)
  const int srow  = lane >> 3;              // row within chunk, == row&7
  const int sslot = (lane & 7) ^ srow;      // pre-swizzled source 16B slot

  f32x4 acc[4][4];
  #pragma unroll
  for (int i = 0; i < 4; ++i)
    #pragma unroll
    for (int jj = 0; jj < 4; ++jj)
      acc[i][jj] = (f32x4){0.f, 0.f, 0.f, 0.f};

  for (int k0 = 0; k0 < K; k0 += BK) {
    #pragma unroll
    for (int i = 0; i < 4; ++i) {
      const int chunk = w * 4 + i;
      const int row = chunk * 8 + srow;
      const u16* ga = A + (size_t)(m0 + row) * K + (k0 + sslot * 8);
      __builtin_amdgcn_global_load_lds((const AS_GLOBAL u32*)(const void*)ga,
                                       (AS_LDS u32*)(Asm + chunk * 512), 16, 0, 0);
      const u16* gb = B + (size_t)(n0 + row) * K + (k0 + sslot * 8);
      __builtin_amdgcn_global_load_lds((const AS_GLOBAL u32*)(const void*)gb,
                                       (AS_LDS u32*)(Bsm + chunk * 512), 16, 0, 0);
    }
    __syncthreads();   // drains vmcnt before barrier -> tiles visible

    #pragma unroll
    for (int kk = 0; kk < BK; kk += 32) {
      const int kbl = kk * 2 + quad * 16;          // linear byte col
      const int sw  = kbl ^ ((l16 & 7) << 4);      // read-side XOR swizzle
      short8v a[4], b[4];
      #pragma unroll
      for (int f = 0; f < 4; ++f) {
        const int arow = wm + f * 16 + l16;        // arow&7 == l16&7
        a[f] = *(const short8v*)((const char*)Asm + arow * 128 + sw);
        const int brow = wn + f * 16 + l16;
        b[f] = *(const short8v*)((const char*)Bsm + brow * 128 + sw);
      }
      #pragma unroll
      for (int fm = 0; fm < 4; ++fm)
        #pragma unroll
        for (int fn = 0; fn < 4; ++fn)
          acc[fm][fn] = __builtin_amdgcn_mfma_f32_16x16x32_bf16(
              a[fm], b[fn], acc[fm][fn], 0, 0, 0);
    }
    __syncthreads();
  }

  // epilogue: C/D layout col = lane&15, row = quad*4 + j  [m89/m91]
  #pragma unroll
  for (int fn = 0; fn < 4; ++fn) {
    const int col = n0 + wn + fn * 16 + l16;
    const float bv = bias[col];
    #pragma unroll
    for (int fm = 0; fm < 4; ++fm) {
      const int rbase2 = m0 + wm + fm * 16 + quad * 4;
      #pragma unroll
      for (int jj = 0; jj < 4; ++jj)
        out[(size_t)(rbase2 + jj) * N + col] = acc[fm][fn][jj] + bv;
    }
  }
}

// ---------------------------------------------------------------------------
extern "C" void kernel_launch(void* const* d_in, const int* in_sizes, int n_in,
                              void* d_out, int out_size, void* d_ws, size_t ws_size,
                              hipStream_t stream) {
  const float* x    = (const float*)d_in[0];   // [8,8192,1024] f32
  const float* wgt  = (const float*)d_in[1];   // [1024,1024] f32
  const float* bias = (const float*)d_in[2];   // [1024] f32
  float* out = (float*)d_out;                  // [8,8192,1024] f32

  const int K = 1024, N = 1024;
  const int M = in_sizes[0] / K;               // 65536

  u16* xq = (u16*)d_ws;                        // 128 MiB bf16
  u16* wq = xq + (size_t)M * K;                // 2 MiB bf16

  const int ngroups = (M * K) / 128;
  quant_kernel<<<ngroups / 16, 256, 0, stream>>>(x, xq);
  wconv_kernel<<<(N * K) / 1024, 256, 0, stream>>>(wgt, wq);
  gemm_kernel<<<(M / BM) * (N / BN), 256, 0, stream>>>(xq, wq, bias, out, M, N, K);
}

// Round 12
// 274.612 us; speedup vs baseline: 1.1891x; 1.1891x over previous
//
#include <hip/hip_runtime.h>

typedef unsigned int u32;
typedef unsigned short u16;

typedef __attribute__((ext_vector_type(8))) short short8v;    // 8 x bf16 bits
typedef __attribute__((ext_vector_type(16))) float f32x16;    // 32x32 C/D

#define AS_GLOBAL __attribute__((address_space(1)))
#define AS_LDS    __attribute__((address_space(3)))

static __device__ __forceinline__ u16 f32_bf16_rne(float f) {
  u32 u = __builtin_bit_cast(u32, f);
  u32 lsb = (u >> 16) & 1u;
  u += 0x7fffu + lsb;
  return (u16)(u >> 16);
}

// ---------------------------------------------------------------------------
// Pass 1: quotient-remainder fake quant, f32 -> bf16 bits.
// One group (GS=128) per 16-lane subgroup; 8 elems/lane.
// base >= 2 always, so reference's sel_mask (base < 1.0) is always false.
// ---------------------------------------------------------------------------
__global__ __launch_bounds__(256) void quant_kernel(
    const float* __restrict__ x, u16* __restrict__ xq) {
  const int tid = blockIdx.x * 256 + threadIdx.x;
  const int grp = tid >> 4;
  const int l   = tid & 15;
  const size_t base_e = (size_t)grp * 128;
  const float* gx = x + base_e;

  float4 v0 = *(const float4*)(gx + l * 4);
  float4 v1 = *(const float4*)(gx + 64 + l * 4);
  float xs[8] = {v0.x, v0.y, v0.z, v0.w, v1.x, v1.y, v1.z, v1.w};

  float mabs = 0.f;
  #pragma unroll
  for (int i = 0; i < 8; ++i) mabs = fmaxf(mabs, fabsf(xs[i]));
  #pragma unroll
  for (int s = 1; s < 16; s <<= 1) mabs = fmaxf(mabs, __shfl_xor(mabs, s, 16));
  mabs = fmaxf(mabs, 1e-8f);

  const float thr = mabs / 7.0f;            // true division: matches np
  float base = 64.f;
  base = (thr <= 32.f) ? 32.f : base;
  base = (thr <= 16.f) ? 16.f : base;
  base = (thr <= 8.f)  ? 8.f  : base;
  base = (thr <= 4.f)  ? 4.f  : base;
  base = (thr <= 2.f)  ? 2.f  : base;
  const float rbase = 1.0f / base;          // exact (power of 2)

  float q[8], r[8];
  float mr = 0.f;
  #pragma unroll
  for (int i = 0; i < 8; ++i) {
    float qq = rintf(xs[i] * rbase);        // == rintf(xs/base), exact scale
    qq = fminf(fmaxf(qq, -7.f), 7.f);
    q[i] = qq;
    r[i] = xs[i] - base * qq;               // exact product, IEEE sub
    mr = fmaxf(mr, fabsf(r[i]));
  }
  #pragma unroll
  for (int s = 1; s < 16; s <<= 1) mr = fmaxf(mr, __shfl_xor(mr, s, 16));
  float rs = fmaxf(mr, 1e-8f) / 7.0f;
  rs = fmaxf(rs, 1e-8f);

  u16 o[8];
  #pragma unroll
  for (int i = 0; i < 8; ++i) {
    float rd = rintf(r[i] / rs);            // IEEE division: matches np
    rd = fminf(fmaxf(rd, -8.f), 7.f) * rs;
    o[i] = f32_bf16_rne(q[i] * base + rd);
  }
  uint2 p0, p1;
  p0.x = (u32)o[0] | ((u32)o[1] << 16);
  p0.y = (u32)o[2] | ((u32)o[3] << 16);
  p1.x = (u32)o[4] | ((u32)o[5] << 16);
  p1.y = (u32)o[6] | ((u32)o[7] << 16);
  *(uint2*)(xq + base_e + l * 4) = p0;
  *(uint2*)(xq + base_e + 64 + l * 4) = p1;
}

// ---------------------------------------------------------------------------
// Pass 2: weight f32 -> bf16 bits.
// ---------------------------------------------------------------------------
__global__ __launch_bounds__(256) void wconv_kernel(
    const float* __restrict__ w, u16* __restrict__ wq) {
  const int i = (blockIdx.x * 256 + threadIdx.x) * 4;
  float4 v = *(const float4*)(w + i);
  uint2 p;
  p.x = (u32)f32_bf16_rne(v.x) | ((u32)f32_bf16_rne(v.y) << 16);
  p.y = (u32)f32_bf16_rne(v.z) | ((u32)f32_bf16_rne(v.w) << 16);
  *(uint2*)(wq + i) = p;
}

// ---------------------------------------------------------------------------
// Pass 3: bf16 MFMA GEMM, PERSISTENT grid=256, 256x256 tile, BK=64,
// 8 waves (2Mx4N), 4 phases/K-step, K-half staging, counted vmcnt(6).
//
// ROUND-12 CHANGE (single variable): MFMA shape 16x16x32 -> 32x32x16.
// Same FLOPs, HALF the MFMA instruction count (16 vs 32 per wave/K-step,
// 8cyc each), same ds_read count & placement, same acc budget (128 f32).
// Rationale: every peak measurement on this chip (m119 2495 TF, hipBLASLt,
// AITER) uses 32x32; fewer/longer MFMAs reduce issue pressure and tolerate
// latency better. All else byte-identical to the r7 persistent skeleton.
//
// Per-wave output 128x64 = 4rt x 2ct tiles of 32x32; acc[4][2] f32x16.
// A-frag (rt,s,ks2): lane reads row = wm+rt*32+(lane&31),
//   k = s*32 + ks2*16 + (lane>>5)*8  (8 bf16 = 16B).
// B-frag (ct,s,ks2): col = wn+ct*32+(lane&31), same k.
// C/D: col = lane&31, row = (reg&3)+8*(reg>>2)+4*(lane>>5)  [m74/m101].
//
// LDS map (16B units, 8192 total): A[p] at p*2048, B[p] at 4096+p*2048;
// within buffer: s*1024 + row*4 + (slot ^ ((row>>1)&3)). Staging and source
// pre-swizzle unchanged; for frag reads (row>>1)&3 == ((lane&31)>>1)&3
// (wm, rt*32, wn, ct*32 all vanish), slot = ks2*2 + (lane>>5).
//
// Stage stream (3 half-tiles ahead, vmcnt(6) at ph3):
//   ph0: B[t+1] k1   ph1: A[t+2] k0   ph2: B[t+2] k0   ph3: A[t+2] k1
// ---------------------------------------------------------------------------
#define BM 256
#define BN 256
#define BK 64

__global__ __launch_bounds__(512, 2) void gemm_kernel(
    const u16* __restrict__ A, const u16* __restrict__ B,
    const float* __restrict__ bias, float* __restrict__ out,
    int M, int N, int K) {
  __shared__ short8v ldsv[8192];   // 128 KiB, 16B units

  const int tid  = threadIdx.x;
  const int w    = tid >> 6;
  const int lane = tid & 63;
  const int l5   = lane & 31;     // row/col within 32x32 tile
  const int kh   = lane >> 5;     // k-half selector (8-elem)

  const int xcd = blockIdx.x & 7;
  const int idx = blockIdx.x >> 3;            // 0..31
  const int n0  = (idx & 3) * BN;
  const int mtl = idx >> 2;                   // 0..7
  const int mtb = xcd * 32 + mtl;
  const int wm = (w >> 2) * 128, wn = (w & 3) * 64;

  // frag read geometry (16B units)
  const int swb = (l5 >> 1) & 3;
  const int swzk0 = kh ^ swb;                 // slot for ks2=0
  const int swzk1 = (2 + kh) ^ swb;           // slot for ks2=1
  int ar4[4], bc4[2];
  #pragma unroll
  for (int rt = 0; rt < 4; ++rt) ar4[rt] = (wm + rt * 32 + l5) * 4;
  #pragma unroll
  for (int ct = 0; ct < 2; ++ct) bc4[ct] = (wn + ct * 32 + l5) * 4;

  auto m0_of = [&](int u) { return (mtb + 8 * (u >> 4)) * BM; };

  // stage one K-half (16 KB): 2 x global_load_lds dwordx4 per thread
  auto stage_half = [&](const u16* __restrict__ G, int base_u, int r0, int k0) {
    #pragma unroll
    for (int i = 0; i < 2; ++i) {
      const int c = w * 2 + i;                       // 0..15 chunks of 1 KiB
      const int row = c * 16 + (lane >> 2);
      const int kslot = (lane & 3) ^ ((lane >> 3) & 3);   // pre-swizzled src
      const u16* g = G + (size_t)(r0 + row) * K + (k0 + kslot * 8);
      __builtin_amdgcn_global_load_lds((const AS_GLOBAL u32*)(const void*)g,
          (AS_LDS u32*)(void*)((char*)ldsv + (size_t)base_u * 16 + c * 1024),
          16, 0, 0);
    }
  };

  // frag reads: s = K-half (0/1), k2 = 16-wide sub of the half
  auto LDA = [&](int base_u, int s, int rt, int k2) {
    return ldsv[base_u + s * 1024 + ar4[rt] + (k2 ? swzk1 : swzk0)];
  };
  auto LDB = [&](int base_u, int s, int ct, int k2) {
    return ldsv[base_u + s * 1024 + bc4[ct] + (k2 ? swzk1 : swzk0)];
  };

  f32x16 acc[4][2];
  #pragma unroll
  for (int rt = 0; rt < 4; ++rt)
    #pragma unroll
    for (int ct = 0; ct < 2; ++ct)
      acc[rt][ct] = (f32x16)(0.f);

  short8v aA[8], aB[8], b0[2], b1[2];   // aX[rt*2+k2]

  const int NTOT = (K / BK) * 4;   // 64 continuous K-steps (4 segments of 16)

  // prologue: tile0's 4 halves + tile1's first 3, stream order
  stage_half(A, 0,           m0_of(0), 0);
  stage_half(B, 4096,        n0, 0);
  stage_half(A, 1024,        m0_of(0), 32);
  stage_half(B, 4096 + 1024, n0, 32);
  stage_half(A, 2048,        m0_of(1), 64);
  stage_half(B, 4096 + 2048, n0, 64);
  stage_half(A, 2048 + 1024, m0_of(1), 96);
  asm volatile("s_waitcnt vmcnt(6)");
  __builtin_amdgcn_s_barrier();

  // pre-issue reads for t=0 phase 0 (parity 0)
  #pragma unroll
  for (int rt = 0; rt < 4; ++rt) {
    aA[rt * 2]     = LDA(0, 0, rt, 0);
    aA[rt * 2 + 1] = LDA(0, 0, rt, 1);
  }
  b0[0] = LDB(4096, 0, 0, 0);
  b0[1] = LDB(4096, 0, 1, 0);

  for (int t = 0; t < NTOT; ++t) {
    const int p   = t & 1;
    const int pAu = p * 2048;
    const int pBu = 4096 + p * 2048;
    const int qAu = (p ^ 1) * 2048;
    const int qBu = 4096 + (p ^ 1) * 2048;
    const int k1s = ((t + 1) & 15) * 64;    // k0 of step t+1
    const int k2s = ((t + 2) & 15) * 64;    // k0 of step t+2

    // -------- phase 0: MFMA (s0,k2=0); read b(s0,k2=1); stage B[t+1]k1
    b1[0] = LDB(pBu, 0, 0, 1);
    b1[1] = LDB(pBu, 0, 1, 1);
    if (t + 1 < NTOT) stage_half(B, qBu + 1024, n0, k1s + 32);
    __builtin_amdgcn_s_barrier();
    __builtin_amdgcn_s_setprio(1);
    #pragma unroll
    for (int rt = 0; rt < 4; ++rt) {
      acc[rt][0] = __builtin_amdgcn_mfma_f32_32x32x16_bf16(aA[rt * 2], b0[0], acc[rt][0], 0, 0, 0);
      acc[rt][1] = __builtin_amdgcn_mfma_f32_32x32x16_bf16(aA[rt * 2], b0[1], acc[rt][1], 0, 0, 0);
    }
    __builtin_amdgcn_s_setprio(0);
    __builtin_amdgcn_s_barrier();

    // -------- phase 1: MFMA (s0,k2=1); read aB(s1 all)+b(s1,k2=0); stage A[t+2]k0
    #pragma unroll
    for (int rt = 0; rt < 4; ++rt) {
      aB[rt * 2]     = LDA(pAu, 1, rt, 0);
      aB[rt * 2 + 1] = LDA(pAu, 1, rt, 1);
    }
    b0[0] = LDB(pBu, 1, 0, 0);
    b0[1] = LDB(pBu, 1, 1, 0);
    if (t + 2 < NTOT) stage_half(A, pAu, m0_of(t + 2), k2s);
    __builtin_amdgcn_s_barrier();
    __builtin_amdgcn_s_setprio(1);
    #pragma unroll
    for (int rt = 0; rt < 4; ++rt) {
      acc[rt][0] = __builtin_amdgcn_mfma_f32_32x32x16_bf16(aA[rt * 2 + 1], b1[0], acc[rt][0], 0, 0, 0);
      acc[rt][1] = __builtin_amdgcn_mfma_f32_32x32x16_bf16(aA[rt * 2 + 1], b1[1], acc[rt][1], 0, 0, 0);
    }
    __builtin_amdgcn_s_setprio(0);
    __builtin_amdgcn_s_barrier();

    // -------- phase 2: MFMA (s1,k2=0); read b(s1,k2=1); stage B[t+2]k0
    b1[0] = LDB(pBu, 1, 0, 1);
    b1[1] = LDB(pBu, 1, 1, 1);
    if (t + 2 < NTOT) stage_half(B, pBu, n0, k2s);
    __builtin_amdgcn_s_barrier();
    __builtin_amdgcn_s_setprio(1);
    #pragma unroll
    for (int rt = 0; rt < 4; ++rt) {
      acc[rt][0] = __builtin_amdgcn_mfma_f32_32x32x16_bf16(aB[rt * 2], b0[0], acc[rt][0], 0, 0, 0);
      acc[rt][1] = __builtin_amdgcn_mfma_f32_32x32x16_bf16(aB[rt * 2], b0[1], acc[rt][1], 0, 0, 0);
    }
    __builtin_amdgcn_s_setprio(0);
    __builtin_amdgcn_s_barrier();

    // -------- phase 3: MFMA (s1,k2=1); stage A[t+2]k1; vmcnt(6);
    //          post-barrier: next step's aA(s0 all) + b(s0,k2=0)
    if (t + 2 < NTOT) stage_half(A, pAu + 1024, m0_of(t + 2), k2s + 32);
    if (t < NTOT - 2)       asm volatile("s_waitcnt vmcnt(6)");
    else if (t == NTOT - 2) asm volatile("s_waitcnt vmcnt(0)");
    __builtin_amdgcn_s_barrier();
    if (t + 1 < NTOT) {
      #pragma unroll
      for (int rt = 0; rt < 4; ++rt) {
        aA[rt * 2]     = LDA(qAu, 0, rt, 0);
        aA[rt * 2 + 1] = LDA(qAu, 0, rt, 1);
      }
      b0[0] = LDB(qBu, 0, 0, 0);
      b0[1] = LDB(qBu, 0, 1, 0);
    }
    __builtin_amdgcn_s_setprio(1);
    #pragma unroll
    for (int rt = 0; rt < 4; ++rt) {
      acc[rt][0] = __builtin_amdgcn_mfma_f32_32x32x16_bf16(aB[rt * 2 + 1], b1[0], acc[rt][0], 0, 0, 0);
      acc[rt][1] = __builtin_amdgcn_mfma_f32_32x32x16_bf16(aB[rt * 2 + 1], b1[1], acc[rt][1], 0, 0, 0);
    }
    __builtin_amdgcn_s_setprio(0);
    __builtin_amdgcn_s_barrier();

    // -------- segment epilogue: flush acc, zero, keep streaming
    if ((t & 15) == 15) {
      const int m0 = m0_of(t);
      #pragma unroll
      for (int ct = 0; ct < 2; ++ct) {
        const int col = n0 + wn + ct * 32 + l5;
        const float bv = bias[col];
        #pragma unroll
        for (int rt = 0; rt < 4; ++rt) {
          const int rb = m0 + wm + rt * 32 + 4 * kh;
          #pragma unroll
          for (int reg = 0; reg < 16; ++reg) {
            const int row = rb + (reg & 3) + 8 * (reg >> 2);
            out[(size_t)row * N + col] = acc[rt][ct][reg] + bv;
          }
        }
      }
      #pragma unroll
      for (int rt = 0; rt < 4; ++rt)
        #pragma unroll
        for (int ct = 0; ct < 2; ++ct)
          acc[rt][ct] = (f32x16)(0.f);
    }
  }
}

// ---------------------------------------------------------------------------
extern "C" void kernel_launch(void* const* d_in, const int* in_sizes, int n_in,
                              void* d_out, int out_size, void* d_ws, size_t ws_size,
                              hipStream_t stream) {
  const float* x    = (const float*)d_in[0];   // [8,8192,1024] f32
  const float* wgt  = (const float*)d_in[1];   // [1024,1024] f32
  const float* bias = (const float*)d_in[2];   // [1024] f32
  float* out = (float*)d_out;                  // [8,8192,1024] f32

  const int K = 1024, N = 1024;
  const int M = in_sizes[0] / K;               // 65536

  u16* xq = (u16*)d_ws;                        // 128 MiB bf16
  u16* wq = xq + (size_t)M * K;                // 2 MiB bf16

  const int ngroups = (M * K) / 128;
  quant_kernel<<<ngroups / 16, 256, 0, stream>>>(x, xq);
  wconv_kernel<<<(N * K) / 1024, 256, 0, stream>>>(wgt, wq);
  gemm_kernel<<<256, 512, 0, stream>>>(xq, wq, bias, out, M, N, K);
}